// Round 6
// baseline (842.747 us; speedup 1.0000x reference)
//
#include <hip/hip_runtime.h>

// ---------------------------------------------------------------------------
// MultiScaleRetention on MI355X (gfx950).  Harness contract (established
// rounds 0-5): inputs fp32, d_out read as fp32; detect() keeps it robust to a
// bf16 harness variant.  CRITICAL lesson from r5: internal buffers are bf16 —
// any GEMM whose A/B is an internal buffer must read it as bf16, never via
// the input-dtype flag (r4/r5 bug: final GEMM read bf16 U with fp32 row
// pitch -> OOB reads of Ccol (~1e27) -> absmax 8.5e25).
//   Math: reference calls _retention_head(qh,qh,qh,...) so Q=K=V=X_h=q_h@W_h.
//   Column normalizer sum_s A[s,t] via suffix scan Z_t = X_t + g*Z_{t+1}.
// Pipeline: detect -> X = proj(q,Wqkv) -> kzc/kdot2 (Ccol) -> retention ->
//   R(bf16, in d_out) -> G = swish(q@Wg+bg) [aliases X] -> gn_gate (in place
//   over G) -> out = U@Wo + bo (fp32 per flag, overwrites d_out).
// ws ~16.4 MB: flag | X 16MB | Carry 128KB | Ccol 256KB.
// ---------------------------------------------------------------------------

constexpr int SEQ  = 2048;
constexpr int BATCH= 4;
constexpr int DIM  = 1024;
constexpr int HDIM = 128;
constexpr int NH   = 8;
constexpr int NBH  = BATCH * NH;   // 32

typedef __bf16 bf16x8 __attribute__((ext_vector_type(8)));
typedef float  f32x4  __attribute__((ext_vector_type(4)));

__device__ __forceinline__ f32x4 mfma16(bf16x8 a, bf16x8 b, f32x4 c) {
  return __builtin_amdgcn_mfma_f32_16x16x32_bf16(a, b, c, 0, 0, 0);
}

__device__ __forceinline__ float bf2f(unsigned short u) {
  return __builtin_bit_cast(float, (unsigned int)u << 16);
}
__device__ __forceinline__ unsigned short f2bf(float f) {
  unsigned int x = __builtin_bit_cast(unsigned int, f);
  x += 0x7fffu + ((x >> 16) & 1u);   // RNE (finite inputs)
  return (unsigned short)(x >> 16);
}

// XOR-swizzled LDS element index for bf16 tiles. RS = row stride (64 or 128).
__device__ __forceinline__ int swz(int row, int col, int RS) {
  int cb  = col >> 3;
  int scb = (cb & ~7) | ((cb ^ (row >> 1)) & 7);
  return row * RS + scb * 8 + (col & 7);
}

// Pack 8 floats -> 8 bf16 (uint4)
__device__ __forceinline__ uint4 pack8(float4 a, float4 b) {
  uint4 o;
  o.x = (unsigned int)f2bf(a.x) | ((unsigned int)f2bf(a.y) << 16);
  o.y = (unsigned int)f2bf(a.z) | ((unsigned int)f2bf(a.w) << 16);
  o.z = (unsigned int)f2bf(b.x) | ((unsigned int)f2bf(b.y) << 16);
  o.w = (unsigned int)f2bf(b.z) | ((unsigned int)f2bf(b.w) << 16);
  return o;
}

// ---------------------------------------------------------------------------
// detect: flag=1 -> inputs bf16; flag=0 -> inputs fp32 (measured: 0 here).
// ---------------------------------------------------------------------------
__global__ void detect(const unsigned short* __restrict__ q, int* __restrict__ flag)
{
  int lane = threadIdx.x;              // 64
  int sane = 0;
  for (int i = lane; i < 1024; i += 64) {
    int e = (q[i] >> 7) & 0xFF;
    sane += (e >= 100 && e <= 140) ? 1 : 0;
  }
  #pragma unroll
  for (int o = 1; o < 64; o <<= 1) sane += __shfl_xor(sane, o);
  if (lane == 0) flag[0] = (sane >= 900) ? 1 : 0;
}

// ---------------------------------------------------------------------------
// 128x128-tile MFMA GEMM, BK=64.  C = A @ B;  A is M x K (lda), B is K x N
// (ldb, natural layout; transposed into Bs[n][k] during staging).
// adt: A dtype 0=fp32, 1=bf16 (internal buffers!), 2=per input flag.
// B and bias always per input flag (they are harness inputs).
// obf: mode-0 output 0=fp32, 1=bf16, 2=per flag (bf16 iff inputs bf16).
// mode 1 (head proj): z=head; A += z*128 cols; B += z*128*128; out bf16 ->
//   X[(b*8+z)*SEQ+s][n].
// ---------------------------------------------------------------------------
__global__ __launch_bounds__(256, 2) void gemm128(
    const void* __restrict__ A, int lda,
    const void* __restrict__ B, int ldb, int K,
    const void* __restrict__ bias, int act,
    void* __restrict__ out, int mode, int adt, int obf,
    const int* __restrict__ dflag)
{
  __shared__ __align__(16) unsigned short As[128 * 64];
  __shared__ __align__(16) unsigned short Bs[128 * 64];
  const int isbf = dflag[0];
  const int abf  = (adt == 1) || (adt == 2 && isbf);   // A is bf16?
  const int tid  = threadIdx.x;
  const int lane = tid & 63;
  const int w    = tid >> 6;
  const int wy   = w >> 1, wx = w & 1;
  const int m15  = lane & 15, qd = lane >> 4;

  const size_t aoff = (mode == 1) ? (size_t)blockIdx.z * 128 : 0;          // col offset
  const size_t boff = (mode == 1) ? (size_t)blockIdx.z * 128 * 128 : 0;    // elem offset
  const size_t arow = (size_t)(blockIdx.y * 128);
  const size_t bcol = (size_t)(blockIdx.x * 128);

  f32x4 zero4 = {0.0f, 0.0f, 0.0f, 0.0f};
  f32x4 acc[4][4];
  #pragma unroll
  for (int i = 0; i < 4; ++i)
    #pragma unroll
    for (int j = 0; j < 4; ++j) acc[i][j] = zero4;

  const int kIters = K >> 6;
  for (int kt = 0; kt < kIters; ++kt) {
    __syncthreads();
    // ---- A staging: 128 rows x 64 k, coalesced ----
    if (abf) {
      const unsigned short* pa = (const unsigned short*)A + aoff + arow * lda + kt * 64;
      #pragma unroll
      for (int g = 0; g < 4; ++g) {
        int idx = tid + g * 256;
        int r = idx >> 3, cb = idx & 7;
        *(uint4*)&As[swz(r, cb * 8, 64)] = *(const uint4*)(pa + (size_t)r * lda + cb * 8);
      }
    } else {
      const float* pa = (const float*)A + aoff + arow * lda + kt * 64;
      #pragma unroll
      for (int g = 0; g < 4; ++g) {
        int idx = tid + g * 256;
        int r = idx >> 3, cb = idx & 7;
        float4 f0 = *(const float4*)(pa + (size_t)r * lda + cb * 8);
        float4 f1 = *(const float4*)(pa + (size_t)r * lda + cb * 8 + 4);
        *(uint4*)&As[swz(r, cb * 8, 64)] = pack8(f0, f1);
      }
    }
    // ---- B staging: transpose 64(k) x 128(n) -> Bs[n][k] ----
    if (isbf) {
      const unsigned short* pb = (const unsigned short*)B + boff + (size_t)(kt * 64) * ldb + bcol;
      #pragma unroll
      for (int g = 0; g < 4; ++g) {
        int idx = tid + g * 256;
        int k = idx >> 4, nb = idx & 15;
        uint4 w4 = *(const uint4*)(pb + (size_t)k * ldb + nb * 8);
        const unsigned short* wp = (const unsigned short*)&w4;
        #pragma unroll
        for (int j = 0; j < 8; ++j)
          Bs[swz(nb * 8 + j, k, 64)] = wp[j];
      }
    } else {
      const float* pb = (const float*)B + boff + (size_t)(kt * 64) * ldb + bcol;
      #pragma unroll
      for (int g = 0; g < 4; ++g) {
        int idx = tid + g * 256;
        int k = idx >> 4, nb = idx & 15;
        float4 f0 = *(const float4*)(pb + (size_t)k * ldb + nb * 8);
        float4 f1 = *(const float4*)(pb + (size_t)k * ldb + nb * 8 + 4);
        Bs[swz(nb * 8 + 0, k, 64)] = f2bf(f0.x);
        Bs[swz(nb * 8 + 1, k, 64)] = f2bf(f0.y);
        Bs[swz(nb * 8 + 2, k, 64)] = f2bf(f0.z);
        Bs[swz(nb * 8 + 3, k, 64)] = f2bf(f0.w);
        Bs[swz(nb * 8 + 4, k, 64)] = f2bf(f1.x);
        Bs[swz(nb * 8 + 5, k, 64)] = f2bf(f1.y);
        Bs[swz(nb * 8 + 6, k, 64)] = f2bf(f1.z);
        Bs[swz(nb * 8 + 7, k, 64)] = f2bf(f1.w);
      }
    }
    __syncthreads();
    #pragma unroll
    for (int kk = 0; kk < 2; ++kk) {
      bf16x8 af[4], bfr[4];
      #pragma unroll
      for (int mt = 0; mt < 4; ++mt)
        af[mt] = *(const bf16x8*)&As[swz(wy * 64 + mt * 16 + m15, kk * 32 + qd * 8, 64)];
      #pragma unroll
      for (int nt = 0; nt < 4; ++nt)
        bfr[nt] = *(const bf16x8*)&Bs[swz(wx * 64 + nt * 16 + m15, kk * 32 + qd * 8, 64)];
      #pragma unroll
      for (int mt = 0; mt < 4; ++mt)
        #pragma unroll
        for (int nt = 0; nt < 4; ++nt)
          acc[mt][nt] = mfma16(af[mt], bfr[nt], acc[mt][nt]);
    }
  }

  const int obf_eff = (obf == 2) ? (isbf ? 1 : 0) : obf;
  #pragma unroll
  for (int mt = 0; mt < 4; ++mt)
    #pragma unroll
    for (int nt = 0; nt < 4; ++nt) {
      int nl = wx * 64 + nt * 16 + m15;
      int n  = blockIdx.x * 128 + nl;
      float bv = 0.0f;
      if (bias) bv = isbf ? bf2f(((const unsigned short*)bias)[n]) : ((const float*)bias)[n];
      #pragma unroll
      for (int r = 0; r < 4; ++r) {
        int ml = wy * 64 + mt * 16 + qd * 4 + r;
        int m  = blockIdx.y * 128 + ml;
        float v = acc[mt][nt][r] + bv;
        if (act == 1) v = v / (1.0f + __expf(-v));   // swish
        if (mode == 0) {
          size_t oi = (size_t)m * (gridDim.x * 128) + n;
          if (obf_eff) ((unsigned short*)out)[oi] = f2bf(v);
          else         ((float*)out)[oi] = v;
        } else {
          int b = m >> 11, s = m & 2047;
          size_t bh = (size_t)(b * NH + blockIdx.z);
          ((unsigned short*)out)[(bh * SEQ + s) * HDIM + n] = f2bf(v);
        }
      }
    }
}

// ---------------------------------------------------------------------------
// kzc: per (bh,d) suffix walk over all t, emitting carries at chunk starts:
// Carry[bh][c][d] = Z_{(c+1)*256}.  X is ours (bf16).
// ---------------------------------------------------------------------------
__global__ void kzc(const unsigned short* __restrict__ X, float* __restrict__ Carry)
{
  const int d  = threadIdx.x;            // 128
  const int bh = blockIdx.x;
  const int h  = bh & 7;
  const float gam = 1.0f - exp2f(-5.0f - (float)h);
  const unsigned short* Xb = X + (size_t)bh * SEQ * HDIM;
  float z = 0.0f;
  for (int c = 7; c >= 0; --c) {
    Carry[((size_t)bh * 8 + c) * HDIM + d] = z;
    for (int t = c * 256 + 255; t >= c * 256; --t)
      z = bf2f(Xb[(size_t)t * HDIM + d]) + gam * z;
  }
}

// ---------------------------------------------------------------------------
// kdot2: per (chunk, bh) one wave recomputes the chunk-local suffix in regs
// (lane owns dims 2*lane, 2*lane+1) and reduces dot(X_t, Z_t) across the wave.
// Ccol[t] = c1 * g^{-t} / (sqrt(colD_t) * max(|colsum_t|, 1)).
// ---------------------------------------------------------------------------
__global__ __launch_bounds__(64) void kdot2(const unsigned short* __restrict__ X,
    const float* __restrict__ Carry, float* __restrict__ Ccol)
{
  const int lane = threadIdx.x;          // 64
  const int c    = blockIdx.x;           // 8 chunks of 256
  const int bh   = blockIdx.y;
  const int h    = bh & 7;
  const float gam    = 1.0f - exp2f(-5.0f - (float)h);
  const float l2g    = log2f(gam);
  const float inv1mg = exp2f(5.0f + (float)h);          // 1/(1-g) exact
  const float c1     = 0.08838834764831845f;            // 1/sqrt(128)
  const unsigned short* Xb = X + (size_t)bh * SEQ * HDIM;
  float2 cr = *(const float2*)(Carry + ((size_t)bh * 8 + c) * HDIM + lane * 2);
  float z0 = 0.0f, z1 = 0.0f;
  float coeff = gam;                     // g^{(c+1)*256 - t}
  for (int t = c * 256 + 255; t >= c * 256; --t) {
    unsigned int xu = *(const unsigned int*)(Xb + (size_t)t * HDIM + lane * 2);
    float x0 = bf2f((unsigned short)(xu & 0xffffu));
    float x1 = bf2f((unsigned short)(xu >> 16));
    z0 = x0 + gam * z0;                  // local suffix incl. x_t
    z1 = x1 + gam * z1;
    float dot = x0 * (z0 + coeff * cr.x) + x1 * (z1 + coeff * cr.y);
    #pragma unroll
    for (int o = 1; o < 64; o <<= 1) dot += __shfl_xor(dot, o);
    if (lane == 0) {
      float colD   = (1.0f - exp2f(l2g * (float)(SEQ - t))) * inv1mg;
      float sq     = sqrtf(colD);
      float colsum = dot * c1 / sq;
      float den    = fmaxf(fabsf(colsum), 1.0f);
      Ccol[(size_t)bh * SEQ + t] = c1 * exp2f(-l2g * (float)t) / (sq * den);
    }
    coeff *= gam;
  }
}

// ---------------------------------------------------------------------------
// Flash-style retention: per (bh, s-tile of 128) iterate 64-wide t-tiles.
// P = (X_s . X_t) * g^s * Ccol_t, masked s>=t, bf16 through LDS (C->A layout
// round trip), then O += P @ V (V = X).  All buffers internal.  R out bf16.
// ---------------------------------------------------------------------------
__global__ __launch_bounds__(256, 2) void retention(
    const unsigned short* __restrict__ X,
    const float* __restrict__ ccol, unsigned short* __restrict__ R)
{
  __shared__ __align__(16) unsigned short sm[24576];  // Ks | VsT | Ps
  unsigned short* Ks  = sm;            // 64 x 128
  unsigned short* VsT = sm + 8192;     // 128 x 64
  unsigned short* Ps  = sm + 16384;    // 128 x 64

  const int tid  = threadIdx.x;
  const int lane = tid & 63;
  const int w    = tid >> 6;
  const int wy   = w >> 1, wx = w & 1;
  const int m15  = lane & 15, qd = lane >> 4;
  const int stile = blockIdx.x;
  const int bh    = blockIdx.y;
  const int h     = bh & 7;
  const int b     = bh >> 3;
  const float gam = 1.0f - exp2f(-5.0f - (float)h);
  const float l2g = log2f(gam);
  const int sbase = stile * 128;
  const unsigned short* Xb = X + (size_t)bh * SEQ * HDIM;
  const float* ccolb = ccol + (size_t)bh * SEQ;

  #pragma unroll
  for (int g = 0; g < 8; ++g) {          // Q tile 128x128 -> sm[0..16384)
    int idx = tid + g * 256;
    int r = idx >> 4, cb = idx & 15;
    *(uint4*)&sm[swz(r, cb * 8, 128)] =
        *(const uint4*)(Xb + (size_t)(sbase + r) * HDIM + cb * 8);
  }
  __syncthreads();
  bf16x8 aq[4][4];
  #pragma unroll
  for (int mt = 0; mt < 4; ++mt)
    #pragma unroll
    for (int kk = 0; kk < 4; ++kk)
      aq[mt][kk] = *(const bf16x8*)&sm[swz(wy * 64 + mt * 16 + m15, kk * 32 + qd * 8, 128)];

  float crow[16];
  #pragma unroll
  for (int mt = 0; mt < 4; ++mt)
    #pragma unroll
    for (int r = 0; r < 4; ++r)
      crow[mt * 4 + r] = exp2f(l2g * (float)(sbase + wy * 64 + mt * 16 + qd * 4 + r));

  f32x4 zero4 = {0.0f, 0.0f, 0.0f, 0.0f};
  f32x4 oacc[4][4];
  #pragma unroll
  for (int i = 0; i < 4; ++i)
    #pragma unroll
    for (int j = 0; j < 4; ++j) oacc[i][j] = zero4;

  const int ntiles = 2 * stile + 2;
  for (int tt = 0; tt < ntiles; ++tt) {
    const int t0 = tt * 64;
    __syncthreads();
    #pragma unroll
    for (int g = 0; g < 4; ++g) {        // Ks: 64 rows x 16 granules
      int idx = tid + g * 256;
      int r = idx >> 4, cb = idx & 15;
      *(uint4*)&Ks[swz(r, cb * 8, 128)] =
          *(const uint4*)(Xb + (size_t)(t0 + r) * HDIM + cb * 8);
    }
    #pragma unroll
    for (int g = 0; g < 4; ++g) {        // VsT: in-LDS transpose (L1-warm)
      int idx = tid + g * 256;
      int t = idx & 63, d0 = (idx >> 6) * 8;
      uint4 w4 = *(const uint4*)(Xb + (size_t)(t0 + t) * HDIM + d0);
      const unsigned short* wsp = (const unsigned short*)&w4;
      #pragma unroll
      for (int j = 0; j < 8; ++j)
        VsT[swz(d0 + j, t, 64)] = wsp[j];
    }
    __syncthreads();

    f32x4 pacc[4][2];
    #pragma unroll
    for (int i = 0; i < 4; ++i) { pacc[i][0] = zero4; pacc[i][1] = zero4; }
    #pragma unroll
    for (int kk = 0; kk < 4; ++kk) {
      bf16x8 bk[2];
      #pragma unroll
      for (int nt = 0; nt < 2; ++nt)
        bk[nt] = *(const bf16x8*)&Ks[swz(wx * 32 + nt * 16 + m15, kk * 32 + qd * 8, 128)];
      #pragma unroll
      for (int mt = 0; mt < 4; ++mt)
        #pragma unroll
        for (int nt = 0; nt < 2; ++nt)
          pacc[mt][nt] = mfma16(aq[mt][kk], bk[nt], pacc[mt][nt]);
    }

    #pragma unroll
    for (int nt = 0; nt < 2; ++nt) {     // decay/scale/mask -> Ps (bf16)
      int tl = wx * 32 + nt * 16 + m15;
      int tg = t0 + tl;
      float cc = ccolb[tg];
      #pragma unroll
      for (int mt = 0; mt < 4; ++mt)
        #pragma unroll
        for (int r = 0; r < 4; ++r) {
          int sl = wy * 64 + mt * 16 + qd * 4 + r;
          int sg = sbase + sl;
          float v = (sg >= tg) ? pacc[mt][nt][r] * crow[mt * 4 + r] * cc : 0.0f;
          Ps[swz(sl, tl, 64)] = f2bf(v);
        }
    }
    __syncthreads();

    #pragma unroll
    for (int kk = 0; kk < 2; ++kk) {     // O += P @ V
      bf16x8 ap[4], bv[4];
      #pragma unroll
      for (int mt = 0; mt < 4; ++mt)
        ap[mt] = *(const bf16x8*)&Ps[swz(wy * 64 + mt * 16 + m15, kk * 32 + qd * 8, 64)];
      #pragma unroll
      for (int nt = 0; nt < 4; ++nt)
        bv[nt] = *(const bf16x8*)&VsT[swz(wx * 64 + nt * 16 + m15, kk * 32 + qd * 8, 64)];
      #pragma unroll
      for (int mt = 0; mt < 4; ++mt)
        #pragma unroll
        for (int nt = 0; nt < 4; ++nt)
          oacc[mt][nt] = mfma16(ap[mt], bv[nt], oacc[mt][nt]);
    }
  }

  #pragma unroll
  for (int mt = 0; mt < 4; ++mt)
    #pragma unroll
    for (int nt = 0; nt < 4; ++nt)
      #pragma unroll
      for (int r = 0; r < 4; ++r) {
        int sg = sbase + wy * 64 + mt * 16 + qd * 4 + r;
        int n  = wx * 64 + nt * 16 + m15;
        R[(size_t)(b * SEQ + sg) * DIM + h * HDIM + n] = f2bf(oacc[mt][nt][r]);
      }
}

// ---------------------------------------------------------------------------
// GroupNorm(32 groups of 32 channels) + beta (per-flag dtype), gated; U
// written IN PLACE over G (ours, bf16).
// ---------------------------------------------------------------------------
__global__ __launch_bounds__(256) void gn_gate(const unsigned short* __restrict__ R,
    const void* __restrict__ beta, unsigned short* __restrict__ GU,
    const int* __restrict__ dflag)
{
  const int isbf = dflag[0];
  const int row = blockIdx.x;
  const int t   = threadIdx.x;
  uint2 xv = *(const uint2*)(R + (size_t)row * DIM + t * 4);
  float x0 = bf2f((unsigned short)(xv.x & 0xffffu)), x1 = bf2f((unsigned short)(xv.x >> 16));
  float x2 = bf2f((unsigned short)(xv.y & 0xffffu)), x3 = bf2f((unsigned short)(xv.y >> 16));
  float s  = x0 + x1 + x2 + x3;
  float ss = x0 * x0 + x1 * x1 + x2 * x2 + x3 * x3;
  #pragma unroll
  for (int m = 1; m <= 4; m <<= 1) {
    s  += __shfl_xor(s, m, 8);
    ss += __shfl_xor(ss, m, 8);
  }
  float mean = s * (1.0f / 32.0f);
  float var  = ss * (1.0f / 32.0f) - mean * mean;
  float rstd = rsqrtf(var + 1e-3f);
  float b0, b1, b2, b3;
  if (isbf) {
    uint2 bv = *(const uint2*)((const unsigned short*)beta + t * 4);
    b0 = bf2f((unsigned short)(bv.x & 0xffffu)); b1 = bf2f((unsigned short)(bv.x >> 16));
    b2 = bf2f((unsigned short)(bv.y & 0xffffu)); b3 = bf2f((unsigned short)(bv.y >> 16));
  } else {
    float4 bv = *(const float4*)((const float*)beta + t * 4);
    b0 = bv.x; b1 = bv.y; b2 = bv.z; b3 = bv.w;
  }
  uint2 gv = *(const uint2*)(GU + (size_t)row * DIM + t * 4);
  float g0 = bf2f((unsigned short)(gv.x & 0xffffu)), g1 = bf2f((unsigned short)(gv.x >> 16));
  float g2 = bf2f((unsigned short)(gv.y & 0xffffu)), g3 = bf2f((unsigned short)(gv.y >> 16));
  unsigned short u0 = f2bf(((x0 - mean) * rstd + b0) * g0);
  unsigned short u1 = f2bf(((x1 - mean) * rstd + b1) * g1);
  unsigned short u2 = f2bf(((x2 - mean) * rstd + b2) * g2);
  unsigned short u3 = f2bf(((x3 - mean) * rstd + b3) * g3);
  uint2 o;
  o.x = (unsigned int)u0 | ((unsigned int)u1 << 16);
  o.y = (unsigned int)u2 | ((unsigned int)u3 << 16);
  *(uint2*)(GU + (size_t)row * DIM + t * 4) = o;
}

// ---------------------------------------------------------------------------
extern "C" void kernel_launch(void* const* d_in, const int* in_sizes, int n_in,
                              void* d_out, int out_size, void* d_ws, size_t ws_size,
                              hipStream_t stream)
{
  (void)in_sizes; (void)n_in; (void)out_size; (void)ws_size;
  const void* q    = d_in[0];
  // d_in[1]=k, d_in[2]=v unused (reference uses q for Q,K,V)
  const void* Wqkv = d_in[3];
  const void* Wg   = d_in[4];
  const void* bg   = d_in[5];
  const void* Wo   = d_in[6];
  const void* bo   = d_in[7];
  const void* beta = d_in[8];

  char* p = (char*)d_ws;
  auto take = [&](size_t bytes) { char* r = p; p += (bytes + 255) & ~(size_t)255; return r; };
  int*  flag = (int*)take(256);
  unsigned short* X  = (unsigned short*)take((size_t)NBH * SEQ * HDIM * 2);  // 16 MB
  float* Carry = (float*)take((size_t)NBH * 8 * HDIM * 4);                   // 128 KB
  float* Ccol  = (float*)take((size_t)NBH * SEQ * 4);                        // 256 KB
  // Aliases (stream-ordered lifetimes):
  unsigned short* Rb = (unsigned short*)d_out; // retention scratch in d_out (16MB bf16)
  unsigned short* G  = X;                      // gate gemm after retention

  detect<<<1, 64, 0, stream>>>((const unsigned short*)q, flag);

  // X = q_h @ W_h per head.  A=q (input dtype), B=Wqkv (input dtype), out bf16.
  gemm128<<<dim3(1, 64, NH), 256, 0, stream>>>(q, DIM, Wqkv, HDIM, HDIM,
                                               nullptr, 0, X, 1, /*adt*/2, /*obf*/1, flag);

  // Column-normalizer: carries then per-chunk dot
  kzc  <<<dim3(NBH, 1, 1), 128, 0, stream>>>(X, Carry);
  kdot2<<<dim3(8, NBH, 1),  64, 0, stream>>>(X, Carry, Ccol);

  // Retention -> Rb (bf16, in d_out)
  retention<<<dim3(16, NBH, 1), 256, 0, stream>>>(X, Ccol, Rb);

  // Gate: G = swish(q @ Wg + bg).  A=q (input), B=Wg (input), out bf16 into X.
  gemm128<<<dim3(8, 64, 1), 256, 0, stream>>>(q, DIM, Wg, DIM, DIM, bg, 1,
                                              G, 0, /*adt*/2, /*obf*/1, flag);

  // GroupNorm + beta, gated; in-place U over G
  gn_gate<<<dim3(BATCH * SEQ, 1, 1), 256, 0, stream>>>(Rb, beta, G, flag);

  // out = U @ Wo + bo.  A=U is OUR bf16 buffer (adt=1!), B=Wo input dtype,
  // output dtype follows input dtype (fp32 here).
  gemm128<<<dim3(8, 64, 1), 256, 0, stream>>>(G, DIM, Wo, DIM, DIM, bo, 0,
                                              d_out, 0, /*adt*/1, /*obf*/2, flag);
}